// Round 1
// baseline (477.222 us; speedup 1.0000x reference)
//
#include <hip/hip_runtime.h>

// MSD via MFMA, atomic-free, K-split x4 + explicit 8-load batches.
// msd[td] = (1/(180*1536)) * sum_i ( S[t] + S[100i] - 2*<x[t],x[100i]> ), t=100i+td
//
// R8 theory: dot kernel latency-bound (VALUBusy 17%, MfmaUtil 1%, HBM 11%,
// occ 39%). Two levers:
//  (a) K split 2 -> 4 planes of 384: 2500 blocks (~9.8 blocks/CU demanded vs
//      8-resident cap) -> ~full 32 waves/CU through most of the kernel.
//  (b) fully-unrolled groups of 2 ks-steps: 8 independent dwordx4 issued
//      before first use; __launch_bounds__(256,8) pins 8 waves/SIMD so the
//      allocator uses the 64-VGPR budget for load buffering (R7 build
//      collapsed to 24 VGPR / ~2 loads in flight).
// Reduce kernel: drop "#pragma unroll 1" -> all ~12 scattered loads in flight.
//
// Block <-> (32 frames, K-plane). FB=32 < 100 makes td unique per block ->
// plain stores into private ws slots; reduce enumerates exactly the valid
// slots. ws usage: 2500 * 640 * 4 = 6.4 MB. bf16 cross term only
// (absmax 7.8e-3 << 4e-2 threshold, validated R6/R7).

typedef __attribute__((ext_vector_type(8))) short bf16x8;
typedef __attribute__((ext_vector_type(4))) float f32x4;

#define ROWF   1536
#define NFRAME 20000
#define NORIG  180
#define WIN    20
#define FB     32
#define NFB    625      // 625*32 = 20000 exactly
#define NKC    4        // K planes
#define KC     384      // 1536 / 4
#define NKS    12       // 384 / 32
#define SLOTS  640      // WIN * FB
#define TDMAX  2000
#define SCALE  (1.0f / (1536.0f * 180.0f))

static __device__ __forceinline__ short f2bf(float f) {
    unsigned u = __builtin_bit_cast(unsigned, f);
    u += 0x7fffu + ((u >> 16) & 1u);
    return (short)(u >> 16);
}

static __device__ __forceinline__ bf16x8 pack8(const float4& v0, const float4& v1) {
    bf16x8 r;
    r[0] = f2bf(v0.x); r[1] = f2bf(v0.y); r[2] = f2bf(v0.z); r[3] = f2bf(v0.w);
    r[4] = f2bf(v1.x); r[5] = f2bf(v1.y); r[6] = f2bf(v1.z); r[7] = f2bf(v1.w);
    return r;
}

static __device__ __forceinline__ float sum8sq(const float4& v0, const float4& v1) {
    return v0.x*v0.x + v0.y*v0.y + v0.z*v0.z + v0.w*v0.w
         + v1.x*v1.x + v1.y*v1.y + v1.z*v1.z + v1.w*v1.w;
}

__global__ __launch_bounds__(256, 8)
void msd_dot_kernel(const float* __restrict__ x, float* __restrict__ ws) {
    __shared__ float sS[FB];   // S-plane-partial for the block's 32 frames
    __shared__ float sO[32];   // S-plane-partial for the 32 origin slots

    const int fb   = blockIdx.x >> 2;    // frame block
    const int kc   = blockIdx.x & 3;     // K plane
    const int t0   = fb * FB;
    const int lane = threadIdx.x & 63;
    const int w    = threadIdx.x >> 6;   // 4 waves
    const int mt   = w >> 1;             // frame half (16 frames)
    const int nt   = w & 1;              // origin half (16 slots)
    const int m    = lane & 15;
    const int quad = lane >> 4;

    const int cmin = t0 / 100;
    int iBase = cmin - (WIN - 1); if (iBase < 0) iBase = 0;

    const int t    = t0 + 16 * mt + m;                 // A row (< 20000 always)
    const int iNom = iBase + 16 * nt + m;              // B origin, nominal
    const int iClp = (iNom < NORIG) ? iNom : (NORIG - 1);

    const float* pA = x + (size_t)t * ROWF + kc * KC + quad * 8;
    const float* pB = x + (size_t)(iClp * 100) * ROWF + kc * KC + quad * 8;

    f32x4 acc = {};
    float sAp = 0.0f, sBp = 0.0f;

    // 6 groups of 2 ks-steps; 8 independent dwordx4 issued per group before
    // any use -> >=8 loads in flight per wave (32 data VGPRs live).
    #pragma unroll
    for (int g = 0; g < NKS / 2; ++g) {
        const float* qA = pA + g * 64;
        const float* qB = pB + g * 64;
        const float4 a00 = *(const float4*)(qA);
        const float4 a01 = *(const float4*)(qA + 4);
        const float4 b00 = *(const float4*)(qB);
        const float4 b01 = *(const float4*)(qB + 4);
        const float4 a10 = *(const float4*)(qA + 32);
        const float4 a11 = *(const float4*)(qA + 36);
        const float4 b10 = *(const float4*)(qB + 32);
        const float4 b11 = *(const float4*)(qB + 36);

        sAp += sum8sq(a00, a01);
        sBp += sum8sq(b00, b01);
        acc = __builtin_amdgcn_mfma_f32_16x16x32_bf16(pack8(a00, a01), pack8(b00, b01),
                                                      acc, 0, 0, 0);
        sAp += sum8sq(a10, a11);
        sBp += sum8sq(b10, b11);
        acc = __builtin_amdgcn_mfma_f32_16x16x32_bf16(pack8(a10, a11), pack8(b10, b11),
                                                      acc, 0, 0, 0);
    }

    // plane-partial S per row: reduce the 4 quad-partials
    sAp += __shfl_xor(sAp, 16, 64); sAp += __shfl_xor(sAp, 32, 64);
    sBp += __shfl_xor(sBp, 16, 64); sBp += __shfl_xor(sBp, 32, 64);
    if (lane < 16) { sS[16 * mt + m] = sAp; sO[16 * nt + m] = sBp; }
    __syncthreads();

    // C/D layout: col = lane&15 (origin slot), row = quad*4 + r (frame-in-tile)
    float* wsb = ws + (size_t)blockIdx.x * SLOTS;
    #pragma unroll
    for (int r = 0; r < 4; ++r) {
        const int j  = 16 * mt + quad * 4 + r;     // frame within block
        const int tt = t0 + j;
        const int c  = tt / 100;
        const int i  = iBase + 16 * nt + m;        // nominal origin of this col
        const int k  = c - i;
        if (k >= 0 && k < WIN && i < NORIG) {
            wsb[k * FB + j] = sS[j] + sO[16 * nt + m] - 2.0f * acc[r];
        }
    }
}

__global__ __launch_bounds__(64)
void msd_reduce_kernel(const float* __restrict__ ws, float* __restrict__ out) {
    const int td   = blockIdx.x;          // 0..1999
    const int lane = threadIdx.x;         // 0..63
    const int k    = td / 100;

    float acc = 0.0f;
    #pragma unroll
    for (int ii = 0; ii < 3; ++ii) {      // ceil(180/64) = 3
        const int i = lane + ii * 64;
        if (i < NORIG) {
            const int t  = 100 * i + td;              // < 20000 always
            const int fb = t >> 5;
            const int sl = k * FB + (t & 31);
            const float* base = ws + (size_t)(fb * NKC) * SLOTS + sl;
            acc += base[0 * SLOTS];
            acc += base[1 * SLOTS];
            acc += base[2 * SLOTS];
            acc += base[3 * SLOTS];
        }
    }
    #pragma unroll
    for (int off = 32; off >= 1; off >>= 1)
        acc += __shfl_xor(acc, off, 64);
    if (lane == 0) out[td] = acc * SCALE;
}

extern "C" void kernel_launch(void* const* d_in, const int* in_sizes, int n_in,
                              void* d_out, int out_size, void* d_ws, size_t ws_size,
                              hipStream_t stream) {
    const float* x = (const float*)d_in[0];
    float* out = (float*)d_out;
    float* ws  = (float*)d_ws;    // needs 2500*640*4 = 6.4 MB

    msd_dot_kernel<<<NFB * NKC, 256, 0, stream>>>(x, ws);
    msd_reduce_kernel<<<TDMAX, 64, 0, stream>>>(ws, out);
}

// Round 2
// 227.312 us; speedup vs baseline: 2.0994x; 2.0994x over previous
//
#include <hip/hip_runtime.h>

// MSD via MFMA, atomic-free. K-split x4, ws in [plane][origin][td] layout.
// msd[td] = (1/(180*1536)) * sum_i ( S[t] + S[100i] - 2*<x[t],x[100i]> ), t=100i+td
//
// R9: R8's launch_bounds(256,8) + hand-widened loads spilled to scratch
// (WRITE_SIZE 2.8MB -> 708MB) -- reverted to R7's compiler-scheduled loop
// (plain launch_bounds(256), unroll 4, ~24-32 VGPR). Kept K-split x4
// (2500 blocks -> full wave slots; R7 was grid-starved at 39% occ).
// Main fix: reduce kernel was ~125 us (!) doing 720 scattered 4B loads per
// block (lane i -> frame 100i -> every load its own cache line). New ws
// layout [kc][i][td]: each (i,td) computed exactly once (t=100i+td maps to
// one frame-block), dot stores there directly (same 16-line/instr scatter
// as before), reduce is lane=td fully-coalesced: 720 contiguous wave-loads
// from a 5.8MB L2/LLC-resident buffer -> ~5 us.
// ws usage: 4 * 180 * 2000 * 4 = 5.76 MB. bf16 cross term only
// (absmax 7.8e-3 << 4e-2 threshold, validated R6/R7).

typedef __attribute__((ext_vector_type(8))) short bf16x8;
typedef __attribute__((ext_vector_type(4))) float f32x4;

#define ROWF   1536
#define NFRAME 20000
#define NORIG  180
#define WIN    20
#define FB     32
#define NFB    625      // 625*32 = 20000 exactly
#define NKC    4        // K planes
#define KC     384      // 1536 / 4
#define NKS    12       // 384 / 32
#define TDMAX  2000
#define PLANE  (NORIG * TDMAX)          // 360000 floats per K-plane
#define SCALE  (1.0f / (1536.0f * 180.0f))

static __device__ __forceinline__ short f2bf(float f) {
    unsigned u = __builtin_bit_cast(unsigned, f);
    u += 0x7fffu + ((u >> 16) & 1u);
    return (short)(u >> 16);
}

static __device__ __forceinline__ bf16x8 pack8(const float4& v0, const float4& v1) {
    bf16x8 r;
    r[0] = f2bf(v0.x); r[1] = f2bf(v0.y); r[2] = f2bf(v0.z); r[3] = f2bf(v0.w);
    r[4] = f2bf(v1.x); r[5] = f2bf(v1.y); r[6] = f2bf(v1.z); r[7] = f2bf(v1.w);
    return r;
}

static __device__ __forceinline__ float sum8sq(const float4& v0, const float4& v1) {
    return v0.x*v0.x + v0.y*v0.y + v0.z*v0.z + v0.w*v0.w
         + v1.x*v1.x + v1.y*v1.y + v1.z*v1.z + v1.w*v1.w;
}

__global__ __launch_bounds__(256)
void msd_dot_kernel(const float* __restrict__ x, float* __restrict__ ws) {
    __shared__ float sS[FB];   // S-plane-partial for the block's 32 frames
    __shared__ float sO[32];   // S-plane-partial for the 32 origin slots

    const int fb   = blockIdx.x >> 2;    // frame block
    const int kc   = blockIdx.x & 3;     // K plane
    const int t0   = fb * FB;
    const int lane = threadIdx.x & 63;
    const int w    = threadIdx.x >> 6;   // 4 waves
    const int mt   = w >> 1;             // frame half (16 frames)
    const int nt   = w & 1;              // origin half (16 slots)
    const int m    = lane & 15;
    const int quad = lane >> 4;

    const int cmin = t0 / 100;
    int iBase = cmin - (WIN - 1); if (iBase < 0) iBase = 0;

    const int t    = t0 + 16 * mt + m;                 // A row (< 20000 always)
    const int iNom = iBase + 16 * nt + m;              // B origin, nominal
    const int iClp = (iNom < NORIG) ? iNom : (NORIG - 1);

    const float* pA = x + (size_t)t * ROWF + kc * KC + quad * 8;
    const float* pB = x + (size_t)(iClp * 100) * ROWF + kc * KC + quad * 8;

    f32x4 acc = {};
    float sAp = 0.0f, sBp = 0.0f;

    #pragma unroll 4
    for (int ks = 0; ks < NKS; ++ks) {
        const float4 a0 = *(const float4*)(pA + ks * 32);
        const float4 a1 = *(const float4*)(pA + ks * 32 + 4);
        const float4 b0 = *(const float4*)(pB + ks * 32);
        const float4 b1 = *(const float4*)(pB + ks * 32 + 4);
        sAp += sum8sq(a0, a1);
        sBp += sum8sq(b0, b1);
        acc = __builtin_amdgcn_mfma_f32_16x16x32_bf16(pack8(a0, a1), pack8(b0, b1),
                                                      acc, 0, 0, 0);
    }

    // plane-partial S per row: reduce the 4 quad-partials
    sAp += __shfl_xor(sAp, 16, 64); sAp += __shfl_xor(sAp, 32, 64);
    sBp += __shfl_xor(sBp, 16, 64); sBp += __shfl_xor(sBp, 32, 64);
    if (lane < 16) { sS[16 * mt + m] = sAp; sO[16 * nt + m] = sBp; }
    __syncthreads();

    // C/D layout: col = lane&15 (origin slot), row = quad*4 + r (frame-in-tile)
    // Store straight into [kc][i][td]: each valid (i,td) is produced by exactly
    // one frame-block (t = 100i+td), so no collisions.
    float* wsp = ws + (size_t)kc * PLANE;
    #pragma unroll
    for (int r = 0; r < 4; ++r) {
        const int j  = 16 * mt + quad * 4 + r;     // frame within block
        const int tt = t0 + j;
        const int c  = tt / 100;
        const int i  = iBase + 16 * nt + m;        // nominal origin of this col
        const int k  = c - i;
        if (k >= 0 && k < WIN && i < NORIG) {
            const int td = tt - 100 * i;           // in [0, 2000) when k in [0,20)
            wsp[(size_t)i * TDMAX + td] = sS[j] + sO[16 * nt + m] - 2.0f * acc[r];
        }
    }
}

__global__ __launch_bounds__(64)
void msd_reduce_kernel(const float* __restrict__ ws, float* __restrict__ out) {
    const int td = blockIdx.x * 64 + threadIdx.x;   // lanes = consecutive td
    if (td >= TDMAX) return;
    float acc = 0.0f;
    #pragma unroll 8
    for (int i = 0; i < NORIG; ++i) {
        const float* p = ws + (size_t)i * TDMAX + td;
        acc += p[0 * PLANE] + p[1 * PLANE] + p[2 * PLANE] + p[3 * PLANE];
    }
    out[td] = acc * SCALE;
}

extern "C" void kernel_launch(void* const* d_in, const int* in_sizes, int n_in,
                              void* d_out, int out_size, void* d_ws, size_t ws_size,
                              hipStream_t stream) {
    const float* x = (const float*)d_in[0];
    float* out = (float*)d_out;
    float* ws  = (float*)d_ws;    // needs 4*180*2000*4 = 5.76 MB

    msd_dot_kernel<<<NFB * NKC, 256, 0, stream>>>(x, ws);
    msd_reduce_kernel<<<(TDMAX + 63) / 64, 64, 0, stream>>>(ws, out);
}

// Round 3
// 202.058 us; speedup vs baseline: 2.3618x; 1.1250x over previous
//
#include <hip/hip_runtime.h>

// MSD via MFMA. R10: LDS-staged dot kernel (coalesced loads), separate S-kernel.
// msd[td] = (1/(180*1536)) * sum_i ( S[t] + S[100i] - 2*<x[t],x[100i]> ), t=100i+td
//
// R9 post-mortem: dot kernel was VMEM-transaction-bound -- fragment loads put
// 64 lanes x 16B across 16 rows (stride 6144B) = ~16-32 lines/instr, TA
// saturated at 39% occupancy (raising occ to 57% changed nothing; VALU 17%,
// HBM 11%, MFMA 1%). Fix: stage tiles global->LDS with lane-contiguous float4
// loads (1 KiB/instr ideal pattern), pack bf16 during staging, read MFMA
// fragments via ds_read_b128 from rows padded to 392 bf16 (784B stride ->
// <=2-way bank aliasing, free per m136). Also removes the 2x intra-block
// operand duplication (491 MB -> 240 MB issued).
// S (sum of squares, f32, full-K) moves to a dedicated coalesced kernel;
// reduce adds S[t]+S[100i] directly, 4 waves/block over i-chunks.
// ws: 4 planes * 180*2000 dot-partials + 20000 S floats = 5.84 MB.
// bf16 cross term only (absmax 7.8e-3 << 4e-2, validated R6-R9).

typedef __attribute__((ext_vector_type(8))) short bf16x8;
typedef __attribute__((ext_vector_type(4))) short bf16x4;
typedef __attribute__((ext_vector_type(4))) float f32x4;

#define ROWF   1536
#define NFRAME 20000
#define NORIG  180
#define WIN    20
#define FB     32
#define NFB    625      // 625*32 = 20000 exactly
#define NKC    4        // K planes
#define KC     384      // 1536 / 4
#define NKS    12       // 384 / 32
#define TDMAX  2000
#define PLANE  (NORIG * TDMAX)          // 360000 floats per K-plane
#define SOFF   (NKC * PLANE)            // S[] lives after the dot planes
#define LROW   392                      // 384 bf16 + 8 pad (16B) -> 784B stride
#define SCALE  (1.0f / (1536.0f * 180.0f))

static __device__ __forceinline__ short f2bf(float f) {
    unsigned u = __builtin_bit_cast(unsigned, f);
    u += 0x7fffu + ((u >> 16) & 1u);
    return (short)(u >> 16);
}

static __device__ __forceinline__ bf16x4 pack4(const float4& v) {
    bf16x4 r;
    r[0] = f2bf(v.x); r[1] = f2bf(v.y); r[2] = f2bf(v.z); r[3] = f2bf(v.w);
    return r;
}

// S[t] = sum over 1536 coords of x[t]^2, f32, fully coalesced. 4 rows/block.
__global__ __launch_bounds__(256)
void msd_s_kernel(const float* __restrict__ x, float* __restrict__ S) {
    const int t    = blockIdx.x * 4 + (threadIdx.x >> 6);
    const int lane = threadIdx.x & 63;
    const float* p = x + (size_t)t * ROWF + lane * 4;
    float a = 0.0f;
    #pragma unroll
    for (int k = 0; k < 6; ++k) {           // 6 * 64 lanes * 4 floats = 1536
        const float4 v = *(const float4*)(p + k * 256);
        a += v.x*v.x + v.y*v.y + v.z*v.z + v.w*v.w;
    }
    #pragma unroll
    for (int off = 32; off >= 1; off >>= 1)
        a += __shfl_xor(a, off, 64);
    if (lane == 0) S[t] = a;
}

__global__ __launch_bounds__(256)
void msd_dot_kernel(const float* __restrict__ x, float* __restrict__ ws) {
    __shared__ short lA[FB * LROW];   // 25088 B
    __shared__ short lB[FB * LROW];   // 25088 B

    const int fb  = blockIdx.x >> 2;    // frame block
    const int kc  = blockIdx.x & 3;     // K plane
    const int t0  = fb * FB;
    const int tid = threadIdx.x;

    const int cmin = t0 / 100;
    int iBase = cmin - (WIN - 1); if (iBase < 0) iBase = 0;

    // ---- stage A: 32 rows x 384 floats, lane-contiguous float4 loads ----
    #pragma unroll
    for (int it = 0; it < 12; ++it) {
        const unsigned seg = it * 256 + tid;      // 0..3071 (32 rows * 96 f4)
        const unsigned r   = seg / 96u;
        const unsigned c4  = seg % 96u;
        const float4 v = *(const float4*)(x + (size_t)(t0 + r) * ROWF
                                            + kc * KC + c4 * 4);
        *(bf16x4*)&lA[r * LROW + c4 * 4] = pack4(v);
    }
    // ---- stage B: 32 origin rows (clamped), same pattern ----
    #pragma unroll
    for (int it = 0; it < 12; ++it) {
        const unsigned seg = it * 256 + tid;
        const unsigned r   = seg / 96u;
        const unsigned c4  = seg % 96u;
        int iNom = iBase + (int)r;
        int iClp = (iNom < NORIG) ? iNom : (NORIG - 1);
        const float4 v = *(const float4*)(x + (size_t)(iClp * 100) * ROWF
                                            + kc * KC + c4 * 4);
        *(bf16x4*)&lB[r * LROW + c4 * 4] = pack4(v);
    }
    __syncthreads();

    // ---- MFMA from LDS ----
    const int lane = tid & 63;
    const int w    = tid >> 6;   // 4 waves
    const int mt   = w >> 1;     // frame half (16 frames)
    const int nt   = w & 1;      // origin half (16 slots)
    const int m    = lane & 15;
    const int quad = lane >> 4;

    const short* pa = &lA[(16 * mt + m) * LROW + quad * 8];
    const short* pb = &lB[(16 * nt + m) * LROW + quad * 8];

    f32x4 acc = {};
    #pragma unroll
    for (int ks = 0; ks < NKS; ++ks) {
        acc = __builtin_amdgcn_mfma_f32_16x16x32_bf16(*(const bf16x8*)(pa + ks * 32),
                                                      *(const bf16x8*)(pb + ks * 32),
                                                      acc, 0, 0, 0);
    }

    // C/D layout: col = lane&15 (origin slot), row = quad*4 + r (frame-in-tile).
    // Store raw dot plane-partial into [kc][i][td]; each valid (i,td) is
    // produced by exactly one frame-block (t = 100i+td), no collisions.
    float* wsp = ws + (size_t)kc * PLANE;
    #pragma unroll
    for (int r = 0; r < 4; ++r) {
        const int j  = 16 * mt + quad * 4 + r;     // frame within block
        const int tt = t0 + j;
        const int c  = tt / 100;
        const int i  = iBase + 16 * nt + m;        // nominal origin of this col
        const int k  = c - i;
        if (k >= 0 && k < WIN && i < NORIG) {
            const int td = tt - 100 * i;           // in [0, 2000)
            wsp[(size_t)i * TDMAX + td] = acc[r];
        }
    }
}

// out[td] = SCALE * sum_i ( S[100i+td] + S[100i] - 2 * sum_kc dot[kc][i][td] )
// 32 blocks x 256: lane = td within a 64-td chunk, wave w covers i in [45w, 45w+45).
__global__ __launch_bounds__(256)
void msd_reduce_kernel(const float* __restrict__ ws, float* __restrict__ out) {
    __shared__ float red[4][64];
    const int lane = threadIdx.x & 63;
    const int w    = threadIdx.x >> 6;
    const int td   = blockIdx.x * 64 + lane;
    const int tdc  = (td < TDMAX) ? td : (TDMAX - 1);   // clamp, no OOB
    const float* S = ws + SOFF;

    float accS = 0.0f, accD = 0.0f;
    #pragma unroll 5
    for (int i = w * 45; i < w * 45 + 45; ++i) {
        accS += S[100 * i + tdc] + S[100 * i];
        const float* p = ws + (size_t)i * TDMAX + tdc;
        accD += p[0] + p[PLANE] + p[2 * PLANE] + p[3 * PLANE];
    }
    red[w][lane] = accS - 2.0f * accD;
    __syncthreads();
    if (w == 0 && td < TDMAX)
        out[td] = (red[0][lane] + red[1][lane] + red[2][lane] + red[3][lane]) * SCALE;
}

extern "C" void kernel_launch(void* const* d_in, const int* in_sizes, int n_in,
                              void* d_out, int out_size, void* d_ws, size_t ws_size,
                              hipStream_t stream) {
    const float* x = (const float*)d_in[0];
    float* out = (float*)d_out;
    float* ws  = (float*)d_ws;    // needs (4*360000 + 20000)*4 = 5.84 MB

    msd_s_kernel<<<NFRAME / 4, 256, 0, stream>>>(x, ws + SOFF);
    msd_dot_kernel<<<NFB * NKC, 256, 0, stream>>>(x, ws);
    msd_reduce_kernel<<<(TDMAX + 63) / 64, 256, 0, stream>>>(ws, out);
}

// Round 4
// 192.627 us; speedup vs baseline: 2.4774x; 1.0490x over previous
//
#include <hip/hip_runtime.h>

// MSD via MFMA. R11: fuse S (sum-of-squares) into the dot kernel's A staging.
// msd[td] = (1/(180*1536)) * sum_i ( S[t] + S[100i] - 2*<x[t],x[100i]> ), t=100i+td
//
// R10 post-mortem: timed window contains ~140 us of harness workspace-poison
// fills (2x 480MB fillBufferAligned @ 71 us, seen in rocprof across R7-R10 as
// a ~120-150 us fixed residual). Controllable kernel sum is only ~55 us:
// S ~20, dot ~30, reduce ~3. The S-kernel is a duplicate full read of x
// (123 MB HBM): the dot grid already stages every (t,kc) segment exactly once
// as an A-tile (fb x kc is a bijection onto frames x K-planes), so S is
// computed inline during A staging from the f32 values BEFORE bf16 packing
// (same precision scheme as before: S f32, cross term bf16; absmax 7.8e-3
// << 4e-2, stable R6-R10). Per-plane S stores (no init needed on poisoned ws);
// reduce sums the 4 planes. A staging switched to row-grouped mapping
// (tid>>3 = row, tid&7 = col-octet) so each thread's 12 loads belong to one
// row: per-row sumsq = 3 shfl_xor within the 8-lane group. Wave still covers
// 8 x 128B fully-consumed segments per load instr.
// ws: 4 dot planes [kc][i][td] (5.76 MB) + 4 S planes [kc][t] (320 KB).

typedef __attribute__((ext_vector_type(8))) short bf16x8;
typedef __attribute__((ext_vector_type(4))) short bf16x4;
typedef __attribute__((ext_vector_type(4))) float f32x4;

#define ROWF   1536
#define NFRAME 20000
#define NORIG  180
#define WIN    20
#define FB     32
#define NFB    625      // 625*32 = 20000 exactly
#define NKC    4        // K planes
#define KC     384      // 1536 / 4
#define NKS    12       // 384 / 32
#define TDMAX  2000
#define PLANE  (NORIG * TDMAX)          // 360000 floats per K-plane
#define SOFF   (NKC * PLANE)            // S planes live after the dot planes
#define LROW   392                      // 384 bf16 + 8 pad -> 784B row stride
#define SCALE  (1.0f / (1536.0f * 180.0f))

static __device__ __forceinline__ short f2bf(float f) {
    unsigned u = __builtin_bit_cast(unsigned, f);
    u += 0x7fffu + ((u >> 16) & 1u);
    return (short)(u >> 16);
}

static __device__ __forceinline__ bf16x4 pack4(const float4& v) {
    bf16x4 r;
    r[0] = f2bf(v.x); r[1] = f2bf(v.y); r[2] = f2bf(v.z); r[3] = f2bf(v.w);
    return r;
}

__global__ __launch_bounds__(256)
void msd_dot_kernel(const float* __restrict__ x, float* __restrict__ ws) {
    __shared__ short lA[FB * LROW];   // 25088 B
    __shared__ short lB[FB * LROW];   // 25088 B

    const int fb  = blockIdx.x >> 2;    // frame block
    const int kc  = blockIdx.x & 3;     // K plane
    const int t0  = fb * FB;
    const int tid = threadIdx.x;

    const int cmin = t0 / 100;
    int iBase = cmin - (WIN - 1); if (iBase < 0) iBase = 0;

    // ---- stage A (row-grouped) + inline f32 sumsq ----
    // 32 rows x 96 float4; thread (r = tid>>3, c8 = tid&7) loads 12 float4s
    // of row r at columns c8 + 8*it. Wave = 8 rows x 128B contiguous segments.
    {
        const int r  = tid >> 3;
        const int c8 = tid & 7;
        const float* src = x + (size_t)(t0 + r) * ROWF + kc * KC + c8 * 4;
        short* dst = &lA[r * LROW + c8 * 4];
        float sq = 0.0f;
        #pragma unroll
        for (int it = 0; it < 12; ++it) {
            const float4 v = *(const float4*)(src + it * 32);
            sq += v.x*v.x + v.y*v.y + v.z*v.z + v.w*v.w;
            *(bf16x4*)(dst + it * 32) = pack4(v);
        }
        sq += __shfl_xor(sq, 1, 64);
        sq += __shfl_xor(sq, 2, 64);
        sq += __shfl_xor(sq, 4, 64);
        if (c8 == 0)
            ws[SOFF + (size_t)kc * NFRAME + t0 + r] = sq;   // plane-partial S
    }
    // ---- stage B: 32 origin rows (clamped), same mapping, no S needed ----
    {
        const int r  = tid >> 3;
        const int c8 = tid & 7;
        const int iNom = iBase + r;
        const int iClp = (iNom < NORIG) ? iNom : (NORIG - 1);
        const float* src = x + (size_t)(iClp * 100) * ROWF + kc * KC + c8 * 4;
        short* dst = &lB[r * LROW + c8 * 4];
        #pragma unroll
        for (int it = 0; it < 12; ++it) {
            const float4 v = *(const float4*)(src + it * 32);
            *(bf16x4*)(dst + it * 32) = pack4(v);
        }
    }
    __syncthreads();

    // ---- MFMA from LDS ----
    const int lane = tid & 63;
    const int w    = tid >> 6;   // 4 waves
    const int mt   = w >> 1;     // frame half (16 frames)
    const int nt   = w & 1;      // origin half (16 slots)
    const int m    = lane & 15;
    const int quad = lane >> 4;

    const short* pa = &lA[(16 * mt + m) * LROW + quad * 8];
    const short* pb = &lB[(16 * nt + m) * LROW + quad * 8];

    f32x4 acc = {};
    #pragma unroll
    for (int ks = 0; ks < NKS; ++ks) {
        acc = __builtin_amdgcn_mfma_f32_16x16x32_bf16(*(const bf16x8*)(pa + ks * 32),
                                                      *(const bf16x8*)(pb + ks * 32),
                                                      acc, 0, 0, 0);
    }

    // C/D layout: col = lane&15 (origin slot), row = quad*4 + r (frame-in-tile).
    // Store raw dot plane-partial into [kc][i][td]; each valid (i,td) is
    // produced by exactly one frame-block (t = 100i+td), no collisions.
    float* wsp = ws + (size_t)kc * PLANE;
    #pragma unroll
    for (int r = 0; r < 4; ++r) {
        const int j  = 16 * mt + quad * 4 + r;     // frame within block
        const int tt = t0 + j;
        const int c  = tt / 100;
        const int i  = iBase + 16 * nt + m;        // nominal origin of this col
        const int k  = c - i;
        if (k >= 0 && k < WIN && i < NORIG) {
            const int td = tt - 100 * i;           // in [0, 2000)
            wsp[(size_t)i * TDMAX + td] = acc[r];
        }
    }
}

// out[td] = SCALE * sum_i ( S[100i+td] + S[100i] - 2 * sum_kc dot[kc][i][td] )
// S[t] = sum_kc Spl[kc][t]. 32 blocks x 256: lane = td within a 64-td chunk,
// wave w covers i in [45w, 45w+45).
__global__ __launch_bounds__(256)
void msd_reduce_kernel(const float* __restrict__ ws, float* __restrict__ out) {
    __shared__ float red[4][64];
    const int lane = threadIdx.x & 63;
    const int w    = threadIdx.x >> 6;
    const int td   = blockIdx.x * 64 + lane;
    const int tdc  = (td < TDMAX) ? td : (TDMAX - 1);   // clamp, no OOB
    const float* Sp = ws + SOFF;

    float acc = 0.0f;
    #pragma unroll 5
    for (int i = w * 45; i < w * 45 + 45; ++i) {
        const int t = 100 * i + tdc;
        const float St = Sp[t]
                       + Sp[1 * NFRAME + t]
                       + Sp[2 * NFRAME + t]
                       + Sp[3 * NFRAME + t];
        const float Si = Sp[100 * i]
                       + Sp[1 * NFRAME + 100 * i]
                       + Sp[2 * NFRAME + 100 * i]
                       + Sp[3 * NFRAME + 100 * i];
        const float* p = ws + (size_t)i * TDMAX + tdc;
        const float d = p[0] + p[PLANE] + p[2 * PLANE] + p[3 * PLANE];
        acc += St + Si - 2.0f * d;
    }
    red[w][lane] = acc;
    __syncthreads();
    if (w == 0 && td < TDMAX)
        out[td] = (red[0][lane] + red[1][lane] + red[2][lane] + red[3][lane]) * SCALE;
}

extern "C" void kernel_launch(void* const* d_in, const int* in_sizes, int n_in,
                              void* d_out, int out_size, void* d_ws, size_t ws_size,
                              hipStream_t stream) {
    const float* x = (const float*)d_in[0];
    float* out = (float*)d_out;
    float* ws  = (float*)d_ws;    // needs (4*360000 + 4*20000)*4 = 6.08 MB

    msd_dot_kernel<<<NFB * NKC, 256, 0, stream>>>(x, ws);
    msd_reduce_kernel<<<(TDMAX + 63) / 64, 256, 0, stream>>>(ws, out);
}